// Round 16
// baseline (148.012 us; speedup 1.0000x reference)
//
#include <hip/hip_runtime.h>

#define IN_DIM  128

typedef __bf16 bf16x8 __attribute__((ext_vector_type(8)));
typedef float  f32x4  __attribute__((ext_vector_type(4)));

static inline size_t align256(size_t x) { return (x + 255) & ~size_t(255); }

// ---------- bf16 helpers (RNE) ----------
__device__ __forceinline__ ushort f2b1(float f) {
    union { float f; uint u; } c; c.f = f;
    uint u = c.u;
    uint r = (u + 0x7FFFu + ((u >> 16) & 1u)) >> 16;
    return (ushort)r;
}
__device__ __forceinline__ float lo_bf(uint v) {
    union { uint u; float f; } c; c.u = v << 16; return c.f;
}
__device__ __forceinline__ float hi_bf(uint v) {
    union { uint u; float f; } c; c.u = v & 0xffff0000u; return c.f;
}
__device__ __forceinline__ float b2f(ushort v) {
    union { uint u; float f; } c; c.u = (uint)v << 16; return c.f;
}

// ---------------- 1) zero deg ----------------

__global__ void zero_kernel(int4* __restrict__ p, int n16) {
    int i = blockIdx.x * blockDim.x + threadIdx.x;
    if (i < n16) p[i] = make_int4(0, 0, 0, 0);
}

// ---------------- 2) hist + deg-independent conversions (one dispatch) ----------------
// blocks [0, histBlocks): rank[e] = atomicAdd(&deg[dst[e]], 1)   (latency/atomic-bound)
// blocks beyond: featb = bf16(x); W1t [128][256]; W2ct [128][128]  (BW-bound, hides under hist)

__global__ __launch_bounds__(256) void hist_conv(
    const int* __restrict__ dst, int* __restrict__ deg, int* __restrict__ rank,
    int E, int histBlocks,
    const float* __restrict__ feats, ushort* __restrict__ featb, int N, int nbF,
    const float* __restrict__ W1, ushort* __restrict__ W1t,
    const float* __restrict__ W2, ushort* __restrict__ W2ct)
{
    int b = blockIdx.x, t = threadIdx.x;
    if (b < histBlocks) {
        int e = b * 256 + t;
        if (e < E) rank[e] = atomicAdd(&deg[dst[e]], 1);
        return;
    }
    int b2 = b - histBlocks;
    if (b2 < nbF) {
        size_t i4 = (size_t)b2 * 256 + t;             // float4 index over N*32
        if (i4 < (size_t)N * 32) {
            size_t i = i4 * 4;
            float4 v = *reinterpret_cast<const float4*>(feats + i);
            ushort4 o;
            o.x = f2b1(v.x); o.y = f2b1(v.y); o.z = f2b1(v.z); o.w = f2b1(v.w);
            *reinterpret_cast<ushort4*>(featb + i) = o;
        }
    } else if (b2 < nbF + 128) {
        int i = (b2 - nbF) * 256 + t;                 // over 256*128
        int k = i >> 7, c = i & 127;
        W1t[(size_t)c * 256 + k] = f2b1(W1[i]);
    } else {
        int i = (b2 - nbF - 128) * 256 + t;           // over 128*128
        int c = i >> 7, k = i & 127;
        float v = (c < 64) ? W2[(size_t)k * 64 + c]
                           : W2[(size_t)(128 + k) * 64 + (c - 64)];
        W2ct[(size_t)c * 128 + k] = f2b1(v);
    }
}

// ---------------- 3) per-1024-chunk exclusive prescan + chunk sums ----------------

__global__ __launch_bounds__(256) void scan_blocks(const int* __restrict__ deg,
                                                   int* __restrict__ pre,
                                                   int* __restrict__ bsum, int n) {
    __shared__ int sh[256];
    int t = threadIdx.x;
    int base = blockIdx.x * 1024 + t * 4;
    int v0 = 0, v1 = 0, v2 = 0, v3 = 0;
    if (base + 3 < n) {
        int4 v = *reinterpret_cast<const int4*>(deg + base);
        v0 = v.x; v1 = v.y; v2 = v.z; v3 = v.w;
    } else {
        if (base     < n) v0 = deg[base];
        if (base + 1 < n) v1 = deg[base + 1];
        if (base + 2 < n) v2 = deg[base + 2];
        if (base + 3 < n) v3 = deg[base + 3];
    }
    int s = v0 + v1 + v2 + v3;
    sh[t] = s;
    __syncthreads();
    for (int off = 1; off < 256; off <<= 1) {
        int x = (t >= off) ? sh[t - off] : 0;
        __syncthreads();
        sh[t] += x;
        __syncthreads();
    }
    int excl = sh[t] - s;
    if (t == 255) bsum[blockIdx.x] = sh[255];
    if (base     < n) pre[base]     = excl;
    if (base + 1 < n) pre[base + 1] = excl + v0;
    if (base + 2 < n) pre[base + 2] = excl + v0 + v1;
    if (base + 3 < n) pre[base + 3] = excl + v0 + v1 + v2;
}

// ---------------- 4) phase2: fill CSR + featbs(=featb*dinv) + pad rows ----------------

template <typename CT>
__global__ __launch_bounds__(256) void phase2_kernel(
    const int* __restrict__ src, const int* __restrict__ dst,
    const int* __restrict__ pre, const int* __restrict__ bsum,
    const int* __restrict__ deg, const int* __restrict__ rank,
    CT* __restrict__ col, int E, int fillBlocks,
    const ushort* __restrict__ featb, ushort* __restrict__ featbs,
    ushort* __restrict__ z2s, int N, int nbF, int nb)
{
    __shared__ int sb[64];
    int b = blockIdx.x, t = threadIdx.x;
    if (t < 64) {   // wave-scan bsum (<=64 entries) -> exclusive prefixes
        int orig = (t < nb) ? bsum[t] : 0;
        int v = orig;
        for (int off = 1; off < 64; off <<= 1) {
            int u = __shfl_up(v, off);
            if (t >= off) v += u;
        }
        sb[t] = v - orig;
    }
    __syncthreads();

    if (b < fillBlocks) {
        int e0 = (b * 256 + t) * 4;
        if (e0 + 3 < E) {
            int4 d4 = *reinterpret_cast<const int4*>(dst + e0);
            int4 r4 = *reinterpret_cast<const int4*>(rank + e0);
            int4 s4 = *reinterpret_cast<const int4*>(src + e0);
            col[pre[d4.x] + sb[d4.x >> 10] + r4.x] = (CT)s4.x;
            col[pre[d4.y] + sb[d4.y >> 10] + r4.y] = (CT)s4.y;
            col[pre[d4.z] + sb[d4.z >> 10] + r4.z] = (CT)s4.z;
            col[pre[d4.w] + sb[d4.w >> 10] + r4.w] = (CT)s4.w;
        } else {
            for (int e = e0; e < E; ++e) {
                int d = dst[e];
                col[pre[d] + sb[d >> 10] + rank[e]] = (CT)src[e];
            }
        }
        return;
    }
    int b2 = b - fillBlocks;
    if (b2 < nbF) {
        size_t i4 = (size_t)b2 * 256 + t;             // ushort4 index over N*32
        if (i4 < (size_t)N * 32) {
            size_t i = i4 * 4;
            ushort4 v = *reinterpret_cast<const ushort4*>(featb + i);
            int node = (int)(i4 >> 5);
            int d = deg[node]; if (d < 1) d = 1;
            float dv = rsqrtf((float)d);
            ushort4 os;
            os.x = f2b1(b2f(v.x) * dv); os.y = f2b1(b2f(v.y) * dv);
            os.z = f2b1(b2f(v.z) * dv); os.w = f2b1(b2f(v.w) * dv);
            *reinterpret_cast<ushort4*>(featbs + i) = os;
        }
    } else {   // single pad block: zero row N of featbs (128) and z2s (64)
        if (t < 32) *reinterpret_cast<uint2*>(featbs + (size_t)N * 128 + t * 4) = make_uint2(0, 0);
        else if (t < 48) *reinterpret_cast<uint2*>(z2s + (size_t)N * 64 + (t - 32) * 4) = make_uint2(0, 0);
    }
}

// ---------------- aggregation layer 1 (dual-node, scalar-address gathers) ----------------

template <typename CT>
__global__ __launch_bounds__(256) void agg_sum128(
    const ushort* __restrict__ Xs, const int* __restrict__ pre,
    const int* __restrict__ bsum, const int* __restrict__ deg,
    const CT* __restrict__ col,
    ushort* __restrict__ X1, int nNodes, int E, int nb)
{
    int w    = (blockIdx.x * blockDim.x + threadIdx.x) >> 6;
    int lane = threadIdx.x & 63;
    int n0 = w * 2;
    if (n0 >= nNodes) return;
    n0 = __builtin_amdgcn_readfirstlane(n0);

    int orig = (lane < nb) ? bsum[lane] : 0;
    int sv = orig;
    for (int off = 1; off < 64; off <<= 1) {
        int u = __shfl_up(sv, off);
        if (lane >= off) sv += u;
    }
    int sbex = sv - orig;

    bool has1 = (n0 + 1) < nNodes;
    int e0a = pre[n0] + __shfl(sbex, n0 >> 10);
    int e1a = (n0 + 1 == nNodes) ? E : pre[n0 + 1] + __shfl(sbex, (n0 + 1) >> 10);
    int e1b = has1 ? ((n0 + 2 == nNodes) ? E : pre[n0 + 2] + __shfl(sbex, (n0 + 2) >> 10)) : e1a;

    int d0 = deg[n0]; if (d0 < 1) d0 = 1;
    int d1 = has1 ? deg[n0 + 1] : 1; if (d1 < 1) d1 = 1;
    float sca = -rsqrtf((float)d0);
    float scb = -rsqrtf((float)d1);
    const uint* Xu = reinterpret_cast<const uint*>(Xs);

    float a0 = 0.f, a1 = 0.f, b0 = 0.f, b1 = 0.f;
    int basea = e0a, baseb = e1a;
    while (basea < e1a || baseb < e1b) {
        int half = lane >> 5, sl = lane & 31;
        int idx = half ? (baseb + sl) : (basea + sl);
        int ee  = half ? e1b : e1a;
        bool okl = idx < ee;
        int cvl = (int)col[okl ? idx : 0];
        int cv  = okl ? cvl : nNodes;
        int cnta = e1a - basea, cntb = e1b - baseb;
        {
            uint va[16], vb[16];
            #pragma unroll
            for (int j = 0; j < 16; ++j) {
                int s0 = __builtin_amdgcn_readlane(cv, j);
                int s1 = __builtin_amdgcn_readlane(cv, 32 + j);
                va[j] = Xu[(uint)(s0 * 64 + lane)];
                vb[j] = Xu[(uint)(s1 * 64 + lane)];
            }
            #pragma unroll
            for (int j = 0; j < 16; ++j) {
                a0 += lo_bf(va[j]); a1 += hi_bf(va[j]);
                b0 += lo_bf(vb[j]); b1 += hi_bf(vb[j]);
            }
        }
        if (cnta > 16 || cntb > 16) {
            uint va[16], vb[16];
            #pragma unroll
            for (int j = 0; j < 16; ++j) {
                int s0 = __builtin_amdgcn_readlane(cv, 16 + j);
                int s1 = __builtin_amdgcn_readlane(cv, 48 + j);
                va[j] = Xu[(uint)(s0 * 64 + lane)];
                vb[j] = Xu[(uint)(s1 * 64 + lane)];
            }
            #pragma unroll
            for (int j = 0; j < 16; ++j) {
                a0 += lo_bf(va[j]); a1 += hi_bf(va[j]);
                b0 += lo_bf(vb[j]); b1 += hi_bf(vb[j]);
            }
        }
        basea += 32; baseb += 32;
    }
    uint oA = (uint)f2b1(a0 * sca) | ((uint)f2b1(a1 * sca) << 16);
    reinterpret_cast<uint*>(X1)[(uint)(n0 * 64 + lane)] = oA;
    if (has1) {
        uint oB = (uint)f2b1(b0 * scb) | ((uint)f2b1(b1 * scb) << 16);
        reinterpret_cast<uint*>(X1)[(uint)((n0 + 1) * 64 + lane)] = oB;
    }
}

// ---------------- aggregation layer 2 (dual-node) ----------------

template <typename CT>
__global__ __launch_bounds__(256) void agg_sum64(
    const ushort* __restrict__ Zs, const int* __restrict__ pre,
    const int* __restrict__ bsum, const int* __restrict__ deg,
    const CT* __restrict__ col,
    float* __restrict__ Y, int nNodes, int E, int nb)
{
    int w    = (blockIdx.x * blockDim.x + threadIdx.x) >> 6;
    int lane = threadIdx.x & 63;
    int n0 = w * 2;
    if (n0 >= nNodes) return;
    n0 = __builtin_amdgcn_readfirstlane(n0);

    int orig = (lane < nb) ? bsum[lane] : 0;
    int sv = orig;
    for (int off = 1; off < 64; off <<= 1) {
        int u = __shfl_up(sv, off);
        if (lane >= off) sv += u;
    }
    int sbex = sv - orig;

    bool has1 = (n0 + 1) < nNodes;
    int e0a = pre[n0] + __shfl(sbex, n0 >> 10);
    int e1a = (n0 + 1 == nNodes) ? E : pre[n0 + 1] + __shfl(sbex, (n0 + 1) >> 10);
    int e1b = has1 ? ((n0 + 2 == nNodes) ? E : pre[n0 + 2] + __shfl(sbex, (n0 + 2) >> 10)) : e1a;

    int d0 = deg[n0]; if (d0 < 1) d0 = 1;
    int d1 = has1 ? deg[n0 + 1] : 1; if (d1 < 1) d1 = 1;
    float sca = -rsqrtf((float)d0);
    float scb = -rsqrtf((float)d1);

    float fa = 0.f, fb = 0.f;
    int basea = e0a, baseb = e1a;
    while (basea < e1a || baseb < e1b) {
        int half = lane >> 5, sl = lane & 31;
        int idx = half ? (baseb + sl) : (basea + sl);
        int ee  = half ? e1b : e1a;
        bool okl = idx < ee;
        int cvl = (int)col[okl ? idx : 0];
        int cv  = okl ? cvl : nNodes;
        int cnta = e1a - basea, cntb = e1b - baseb;
        {
            ushort va[16], vb[16];
            #pragma unroll
            for (int j = 0; j < 16; ++j) {
                int s0 = __builtin_amdgcn_readlane(cv, j);
                int s1 = __builtin_amdgcn_readlane(cv, 32 + j);
                va[j] = Zs[(uint)(s0 * 64 + lane)];
                vb[j] = Zs[(uint)(s1 * 64 + lane)];
            }
            #pragma unroll
            for (int j = 0; j < 16; ++j) {
                fa += lo_bf((uint)va[j]);
                fb += lo_bf((uint)vb[j]);
            }
        }
        if (cnta > 16 || cntb > 16) {
            ushort va[16], vb[16];
            #pragma unroll
            for (int j = 0; j < 16; ++j) {
                int s0 = __builtin_amdgcn_readlane(cv, 16 + j);
                int s1 = __builtin_amdgcn_readlane(cv, 48 + j);
                va[j] = Zs[(uint)(s0 * 64 + lane)];
                vb[j] = Zs[(uint)(s1 * 64 + lane)];
            }
            #pragma unroll
            for (int j = 0; j < 16; ++j) {
                fa += lo_bf((uint)va[j]);
                fb += lo_bf((uint)vb[j]);
            }
        }
        basea += 32; baseb += 32;
    }
    Y[(uint)(n0 * 64 + lane)] += fa * sca;
    if (has1)
        Y[(uint)((n0 + 1) * 64 + lane)] += fb * scb;
}

// ---------------- MFMA GEMM layer 1: h1 = [featb | x1] @ W1 + b1 ----------------

__global__ __launch_bounds__(256) void gemm_mfma1(
    const ushort* __restrict__ XA, const ushort* __restrict__ XB,
    const ushort* __restrict__ Wt, const float* __restrict__ bias,
    ushort* __restrict__ Y, int nNodes)
{
    __shared__ ushort wlds[128 * 256];
    int t = threadIdx.x;

    #pragma unroll
    for (int it = 0; it < 16; ++it) {
        int i = it * 256 + t;
        int c = i >> 5;
        int o = (i & 31) << 4;
        bf16x8 v = *reinterpret_cast<const bf16x8*>(Wt + ((size_t)c << 8) + (o >> 1));
        *reinterpret_cast<bf16x8*>((char*)wlds + ((size_t)c << 9) + (o ^ ((c & 7) << 4))) = v;
    }
    __syncthreads();

    int wave = t >> 6, lane = t & 63;
    int r16 = lane & 15, g = lane >> 4;
    int nodeBase = blockIdx.x * 128 + wave * 32;

    int arow0 = nodeBase + r16;       if (arow0 > nNodes - 1) arow0 = nNodes - 1;
    int arow1 = nodeBase + 16 + r16;  if (arow1 > nNodes - 1) arow1 = nNodes - 1;
    const ushort* pA0 = XA + (size_t)arow0 * 128;
    const ushort* pA1 = XA + (size_t)arow1 * 128;
    const ushort* pB0 = XB + (size_t)arow0 * 128;
    const ushort* pB1 = XB + (size_t)arow1 * 128;

    f32x4 acc0[8], acc1[8];
    #pragma unroll
    for (int i = 0; i < 8; ++i) { acc0[i] = f32x4{0,0,0,0}; acc1[i] = f32x4{0,0,0,0}; }

    #pragma unroll
    for (int kb = 0; kb < 8; ++kb) {
        int kk = (kb & 3) * 32 + g * 8;
        bf16x8 a0 = *reinterpret_cast<const bf16x8*>(((kb < 4) ? pA0 : pB0) + kk);
        bf16x8 a1 = *reinterpret_cast<const bf16x8*>(((kb < 4) ? pA1 : pB1) + kk);
        int o = kb * 64 + g * 16;
        #pragma unroll
        for (int ct = 0; ct < 8; ++ct) {
            int c = ct * 16 + r16;
            bf16x8 bfrag = *reinterpret_cast<const bf16x8*>(
                (const char*)wlds + ((size_t)c << 9) + (o ^ ((c & 7) << 4)));
            acc0[ct] = __builtin_amdgcn_mfma_f32_16x16x32_bf16(a0, bfrag, acc0[ct], 0, 0, 0);
            acc1[ct] = __builtin_amdgcn_mfma_f32_16x16x32_bf16(a1, bfrag, acc1[ct], 0, 0, 0);
        }
    }

    #pragma unroll
    for (int ct = 0; ct < 8; ++ct) {
        float bv = bias[ct * 16 + r16];
        #pragma unroll
        for (int r = 0; r < 4; ++r) {
            int orow0 = nodeBase + g * 4 + r;
            int orow1 = orow0 + 16;
            if (orow0 < nNodes) Y[(size_t)orow0 * 128 + ct * 16 + r16] = f2b1(acc0[ct][r] + bv);
            if (orow1 < nNodes) Y[(size_t)orow1 * 128 + ct * 16 + r16] = f2b1(acc1[ct][r] + bv);
        }
    }
}

// ---------------- MFMA GEMM layer 2 fused: [y_top | z2s] = h1 @ W2c, K=128 ----------------

__global__ __launch_bounds__(256) void gemm_mfma2(
    const ushort* __restrict__ H1, const ushort* __restrict__ W2ct,
    const float* __restrict__ bias, const int* __restrict__ deg,
    float* __restrict__ Yout, ushort* __restrict__ Z2, int nNodes)
{
    __shared__ ushort wlds[128 * 128];
    int t = threadIdx.x;

    #pragma unroll
    for (int it = 0; it < 8; ++it) {
        int i = it * 256 + t;
        int c = i >> 4;
        int o = (i & 15) << 4;
        bf16x8 v = *reinterpret_cast<const bf16x8*>(W2ct + ((size_t)c << 7) + (o >> 1));
        *reinterpret_cast<bf16x8*>((char*)wlds + ((size_t)c << 8) + (o ^ ((c & 7) << 4))) = v;
    }
    __syncthreads();

    int wave = t >> 6, lane = t & 63;
    int r16 = lane & 15, g = lane >> 4;
    int nodeBase = blockIdx.x * 128 + wave * 32;

    int arow0 = nodeBase + r16;       if (arow0 > nNodes - 1) arow0 = nNodes - 1;
    int arow1 = nodeBase + 16 + r16;  if (arow1 > nNodes - 1) arow1 = nNodes - 1;
    const ushort* p0 = H1 + (size_t)arow0 * 128;
    const ushort* p1 = H1 + (size_t)arow1 * 128;

    f32x4 acc0[8], acc1[8];
    #pragma unroll
    for (int i = 0; i < 8; ++i) { acc0[i] = f32x4{0,0,0,0}; acc1[i] = f32x4{0,0,0,0}; }

    #pragma unroll
    for (int kb = 0; kb < 4; ++kb) {
        int kk = kb * 32 + g * 8;
        bf16x8 v0 = *reinterpret_cast<const bf16x8*>(p0 + kk);
        bf16x8 v1 = *reinterpret_cast<const bf16x8*>(p1 + kk);
        int o = kb * 64 + g * 16;
        #pragma unroll
        for (int ct = 0; ct < 8; ++ct) {
            int c = ct * 16 + r16;
            bf16x8 bfrag = *reinterpret_cast<const bf16x8*>(
                (const char*)wlds + ((size_t)c << 8) + (o ^ ((c & 7) << 4)));
            acc0[ct] = __builtin_amdgcn_mfma_f32_16x16x32_bf16(v0, bfrag, acc0[ct], 0, 0, 0);
            acc1[ct] = __builtin_amdgcn_mfma_f32_16x16x32_bf16(v1, bfrag, acc1[ct], 0, 0, 0);
        }
    }

    float dv0[4], dv1[4];
    #pragma unroll
    for (int r = 0; r < 4; ++r) {
        int o0 = nodeBase + g * 4 + r;      if (o0 > nNodes - 1) o0 = nNodes - 1;
        int o1 = nodeBase + 16 + g * 4 + r; if (o1 > nNodes - 1) o1 = nNodes - 1;
        int d0 = deg[o0]; if (d0 < 1) d0 = 1;
        int d1 = deg[o1]; if (d1 < 1) d1 = 1;
        dv0[r] = rsqrtf((float)d0);
        dv1[r] = rsqrtf((float)d1);
    }

    #pragma unroll
    for (int ct = 0; ct < 8; ++ct) {
        float bv = (ct < 4) ? bias[ct * 16 + r16] : 0.f;
        #pragma unroll
        for (int r = 0; r < 4; ++r) {
            int orow0 = nodeBase + g * 4 + r;
            int orow1 = orow0 + 16;
            if (ct < 4) {
                if (orow0 < nNodes) Yout[(size_t)orow0 * 64 + ct * 16 + r16] = acc0[ct][r] + bv;
                if (orow1 < nNodes) Yout[(size_t)orow1 * 64 + ct * 16 + r16] = acc1[ct][r] + bv;
            } else {
                if (orow0 < nNodes) Z2[(size_t)orow0 * 64 + (ct - 4) * 16 + r16] = f2b1(acc0[ct][r] * dv0[r]);
                if (orow1 < nNodes) Z2[(size_t)orow1 * 64 + (ct - 4) * 16 + r16] = f2b1(acc1[ct][r] * dv1[r]);
            }
        }
    }
}

// ---------------- host ----------------

extern "C" void kernel_launch(void* const* d_in, const int* in_sizes, int n_in,
                              void* d_out, int out_size, void* d_ws, size_t ws_size,
                              hipStream_t stream)
{
    const float* feats = (const float*)d_in[0];
    const int*   src   = (const int*)d_in[1];
    const int*   dst   = (const int*)d_in[2];
    const float* W1    = (const float*)d_in[3];
    const float* b1    = (const float*)d_in[4];
    const float* W2    = (const float*)d_in[5];
    const float* b2    = (const float*)d_in[6];
    float* out = (float*)d_out;

    const int N = in_sizes[0] / IN_DIM;
    const int E = in_sizes[1];
    const int NB = (N + 1023) / 1024;

    char* ws = (char*)d_ws;
    size_t off = 0;
    int*    deg    = (int*)(ws + off);    off = align256(off + (size_t)N * 4);
    int*    pre    = (int*)(ws + off);    off = align256(off + (size_t)N * 4);
    int*    bsum   = (int*)(ws + off);    off = align256(off + (size_t)64 * 4);
    int*    rank   = (int*)(ws + off);    off = align256(off + (size_t)E * 4);
    void*   colv   = (void*)(ws + off);   off = align256(off + (size_t)E * 4);
    ushort* featb  = (ushort*)(ws + off); off = align256(off + (size_t)N * 128 * 2);
    ushort* featbs = (ushort*)(ws + off); off = align256(off + (size_t)(N + 1) * 128 * 2);
    ushort* x1b    = (ushort*)(ws + off); off = align256(off + (size_t)N * 128 * 2);
    ushort* h1b    = (ushort*)(ws + off); off = align256(off + (size_t)N * 128 * 2);
    ushort* z2s    = (ushort*)(ws + off); off = align256(off + (size_t)(N + 1) * 64 * 2);
    ushort* W1t    = (ushort*)(ws + off); off = align256(off + (size_t)256 * 128 * 2);
    ushort* W2ct   = (ushort*)(ws + off); off = align256(off + (size_t)128 * 128 * 2);

    const bool small = (N <= 65535);
    const int nbF = (N * 32 + 255) / 256;

    // 1) zero deg
    const int n16 = (N + 3) / 4;
    zero_kernel<<<(n16 + 255) / 256, 256, 0, stream>>>((int4*)deg, n16);

    // 2) hist + deg-independent conversions (conv hides under atomic latency)
    const int histBlocks = (E + 255) / 256;
    hist_conv<<<histBlocks + nbF + 128 + 64, 256, 0, stream>>>(
        dst, deg, rank, E, histBlocks, feats, featb, N, nbF, W1, W1t, W2, W2ct);

    // 3) chunk prescan
    scan_blocks<<<NB, 256, 0, stream>>>(deg, pre, bsum, N);

    // 4) fill CSR + featbs (+ pad rows)
    const int fillBlocks = ((E + 3) / 4 + 255) / 256;
    if (small)
        phase2_kernel<ushort><<<fillBlocks + nbF + 1, 256, 0, stream>>>(
            src, dst, pre, bsum, deg, rank, (ushort*)colv, E, fillBlocks,
            featb, featbs, z2s, N, nbF, NB);
    else
        phase2_kernel<uint><<<fillBlocks + nbF + 1, 256, 0, stream>>>(
            src, dst, pre, bsum, deg, rank, (uint*)colv, E, fillBlocks,
            featb, featbs, z2s, N, nbF, NB);

    const int nPairWaves = (N + 1) / 2;
    const int aggBlocks = (nPairWaves * 64 + 255) / 256;
    const int gemmBlocks = (N + 127) / 128;

    // 5) agg1 ; 6) gemm1
    if (small)
        agg_sum128<ushort><<<aggBlocks, 256, 0, stream>>>(featbs, pre, bsum, deg, (const ushort*)colv, x1b, N, E, NB);
    else
        agg_sum128<uint><<<aggBlocks, 256, 0, stream>>>(featbs, pre, bsum, deg, (const uint*)colv, x1b, N, E, NB);
    gemm_mfma1<<<gemmBlocks, 256, 0, stream>>>(featb, x1b, W1t, b1, h1b, N);

    // 7) gemm2 ; 8) agg2
    gemm_mfma2<<<gemmBlocks, 256, 0, stream>>>(h1b, W2ct, b2, deg, out, z2s, N);
    if (small)
        agg_sum64<ushort><<<aggBlocks, 256, 0, stream>>>(z2s, pre, bsum, deg, (const ushort*)colv, out, N, E, NB);
    else
        agg_sum64<uint><<<aggBlocks, 256, 0, stream>>>(z2s, pre, bsum, deg, (const uint*)colv, out, N, E, NB);
}

// Round 17
// 142.761 us; speedup vs baseline: 1.0368x; 1.0368x over previous
//
#include <hip/hip_runtime.h>

#define IN_DIM  128

typedef __bf16 bf16x8 __attribute__((ext_vector_type(8)));
typedef float  f32x4  __attribute__((ext_vector_type(4)));

static inline size_t align256(size_t x) { return (x + 255) & ~size_t(255); }

// ---------- bf16 helpers (RNE) ----------
__device__ __forceinline__ ushort f2b1(float f) {
    union { float f; uint u; } c; c.f = f;
    uint u = c.u;
    uint r = (u + 0x7FFFu + ((u >> 16) & 1u)) >> 16;
    return (ushort)r;
}
__device__ __forceinline__ float lo_bf(uint v) {
    union { uint u; float f; } c; c.u = v << 16; return c.f;
}
__device__ __forceinline__ float hi_bf(uint v) {
    union { uint u; float f; } c; c.u = v & 0xffff0000u; return c.f;
}

// ---------------- 1) zero deg ----------------

__global__ void zero_kernel(int4* __restrict__ p, int n16) {
    int i = blockIdx.x * blockDim.x + threadIdx.x;
    if (i < n16) p[i] = make_int4(0, 0, 0, 0);
}

// ---------------- 2) hist + weight conversions (W-conv hides under atomic latency) ----------------

__global__ __launch_bounds__(256) void hist_conv(
    const int* __restrict__ dst, int* __restrict__ deg, int* __restrict__ rank,
    int E, int histBlocks,
    const float* __restrict__ W1, ushort* __restrict__ W1t,
    const float* __restrict__ W2, ushort* __restrict__ W2ct)
{
    int b = blockIdx.x, t = threadIdx.x;
    if (b < histBlocks) {
        int e = b * 256 + t;
        if (e < E) rank[e] = atomicAdd(&deg[dst[e]], 1);
        return;
    }
    int b2 = b - histBlocks;
    if (b2 < 128) {
        int i = b2 * 256 + t;                 // over 256*128
        int k = i >> 7, c = i & 127;
        W1t[(size_t)c * 256 + k] = f2b1(W1[i]);
    } else {
        int i = (b2 - 128) * 256 + t;         // over 128*128
        int c = i >> 7, k = i & 127;
        float v = (c < 64) ? W2[(size_t)k * 64 + c]
                           : W2[(size_t)(128 + k) * 64 + (c - 64)];
        W2ct[(size_t)c * 128 + k] = f2b1(v);
    }
}

// ---------------- 3) per-1024-chunk exclusive prescan + chunk sums ----------------

__global__ __launch_bounds__(256) void scan_blocks(const int* __restrict__ deg,
                                                   int* __restrict__ pre,
                                                   int* __restrict__ bsum, int n) {
    __shared__ int sh[256];
    int t = threadIdx.x;
    int base = blockIdx.x * 1024 + t * 4;
    int v0 = 0, v1 = 0, v2 = 0, v3 = 0;
    if (base + 3 < n) {
        int4 v = *reinterpret_cast<const int4*>(deg + base);
        v0 = v.x; v1 = v.y; v2 = v.z; v3 = v.w;
    } else {
        if (base     < n) v0 = deg[base];
        if (base + 1 < n) v1 = deg[base + 1];
        if (base + 2 < n) v2 = deg[base + 2];
        if (base + 3 < n) v3 = deg[base + 3];
    }
    int s = v0 + v1 + v2 + v3;
    sh[t] = s;
    __syncthreads();
    for (int off = 1; off < 256; off <<= 1) {
        int x = (t >= off) ? sh[t - off] : 0;
        __syncthreads();
        sh[t] += x;
        __syncthreads();
    }
    int excl = sh[t] - s;
    if (t == 255) bsum[blockIdx.x] = sh[255];
    if (base     < n) pre[base]     = excl;
    if (base + 1 < n) pre[base + 1] = excl + v0;
    if (base + 2 < n) pre[base + 2] = excl + v0 + v1;
    if (base + 3 < n) pre[base + 3] = excl + v0 + v1 + v2;
}

// ---------------- 4) scan_add: rowptr = pre + scan(bsum); dinv = rsqrt(deg) ----------------

__global__ __launch_bounds__(256) void scan_add(
    const int* __restrict__ pre, const int* __restrict__ bsum,
    const int* __restrict__ deg,
    int* __restrict__ rowptr, float* __restrict__ dinv,
    int n, int E, int nb)
{
    __shared__ int sb[64];
    int t = threadIdx.x;
    if (t < 64) {
        int orig = (t < nb) ? bsum[t] : 0;
        int v = orig;
        for (int off = 1; off < 64; off <<= 1) {
            int u = __shfl_up(v, off);
            if (t >= off) v += u;
        }
        sb[t] = v - orig;   // exclusive
    }
    __syncthreads();
    int i = blockIdx.x * blockDim.x + t;
    if (i < n) {
        rowptr[i] = pre[i] + sb[i >> 10];
        int d = deg[i]; if (d < 1) d = 1;
        dinv[i] = rsqrtf((float)d);
    }
    if (i == 0) rowptr[n] = E;
}

// ---------------- 5) phase2: fill CSR + featb/featbs conversions + pad rows ----------------

template <typename CT>
__global__ __launch_bounds__(256) void phase2_kernel(
    const int* __restrict__ src, const int* __restrict__ dst,
    const int* __restrict__ rowptr, const int* __restrict__ rank,
    CT* __restrict__ col, int E, int fillBlocks,
    const float* __restrict__ feats, const float* __restrict__ dinv,
    ushort* __restrict__ featb, ushort* __restrict__ featbs,
    ushort* __restrict__ z2s, int N, int nbF)
{
    int b = blockIdx.x, t = threadIdx.x;
    if (b < fillBlocks) {
        int e0 = (b * 256 + t) * 4;
        if (e0 + 3 < E) {
            int4 d4 = *reinterpret_cast<const int4*>(dst + e0);
            int4 r4 = *reinterpret_cast<const int4*>(rank + e0);
            int4 s4 = *reinterpret_cast<const int4*>(src + e0);
            col[rowptr[d4.x] + r4.x] = (CT)s4.x;
            col[rowptr[d4.y] + r4.y] = (CT)s4.y;
            col[rowptr[d4.z] + r4.z] = (CT)s4.z;
            col[rowptr[d4.w] + r4.w] = (CT)s4.w;
        } else {
            for (int e = e0; e < E; ++e)
                col[rowptr[dst[e]] + rank[e]] = (CT)src[e];
        }
        return;
    }
    int b2 = b - fillBlocks;
    if (b2 < nbF) {
        size_t i4 = (size_t)b2 * 256 + t;         // float4 index
        if (i4 < (size_t)N * 32) {
            size_t i = i4 * 4;
            float4 v = *reinterpret_cast<const float4*>(feats + i);
            float dv = dinv[i >> 7];              // 4 consecutive floats share a node
            ushort4 o, os;
            o.x  = f2b1(v.x);      o.y  = f2b1(v.y);      o.z  = f2b1(v.z);      o.w  = f2b1(v.w);
            os.x = f2b1(v.x * dv); os.y = f2b1(v.y * dv); os.z = f2b1(v.z * dv); os.w = f2b1(v.w * dv);
            *reinterpret_cast<ushort4*>(featb  + i) = o;
            *reinterpret_cast<ushort4*>(featbs + i) = os;
        }
    } else {   // single pad block: zero row N of featbs (128) and z2s (64)
        if (t < 32) *reinterpret_cast<uint2*>(featbs + (size_t)N * 128 + t * 4) = make_uint2(0, 0);
        else if (t < 48) *reinterpret_cast<uint2*>(z2s + (size_t)N * 64 + (t - 32) * 4) = make_uint2(0, 0);
    }
}

// ---------------- aggregation layer 1 (dual-node, scalar-address gathers) ----------------

template <typename CT>
__global__ __launch_bounds__(256) void agg_sum128(
    const ushort* __restrict__ Xs, const int* __restrict__ rowptr,
    const CT* __restrict__ col, const float* __restrict__ dinv,
    ushort* __restrict__ X1, int nNodes)
{
    int w    = (blockIdx.x * blockDim.x + threadIdx.x) >> 6;
    int lane = threadIdx.x & 63;
    int n0 = w * 2;
    if (n0 >= nNodes) return;
    n0 = __builtin_amdgcn_readfirstlane(n0);
    bool has1 = (n0 + 1) < nNodes;
    int e0a = rowptr[n0];
    int e1a = rowptr[n0 + 1];
    int e1b = has1 ? rowptr[n0 + 2] : e1a;
    float sca = -dinv[n0];
    float scb = -dinv[has1 ? n0 + 1 : n0];
    const uint* Xu = reinterpret_cast<const uint*>(Xs);

    float a0 = 0.f, a1 = 0.f, b0 = 0.f, b1 = 0.f;
    int basea = e0a, baseb = e1a;
    while (basea < e1a || baseb < e1b) {
        int half = lane >> 5, sl = lane & 31;
        int idx = half ? (baseb + sl) : (basea + sl);
        int ee  = half ? e1b : e1a;
        bool okl = idx < ee;
        int cvl = (int)col[okl ? idx : 0];
        int cv  = okl ? cvl : nNodes;            // pad -> zero row
        int cnta = e1a - basea, cntb = e1b - baseb;
        {
            uint va[16], vb[16];
            #pragma unroll
            for (int j = 0; j < 16; ++j) {
                int s0 = __builtin_amdgcn_readlane(cv, j);
                int s1 = __builtin_amdgcn_readlane(cv, 32 + j);
                va[j] = Xu[(uint)(s0 * 64 + lane)];
                vb[j] = Xu[(uint)(s1 * 64 + lane)];
            }
            #pragma unroll
            for (int j = 0; j < 16; ++j) {
                a0 += lo_bf(va[j]); a1 += hi_bf(va[j]);
                b0 += lo_bf(vb[j]); b1 += hi_bf(vb[j]);
            }
        }
        if (cnta > 16 || cntb > 16) {
            uint va[16], vb[16];
            #pragma unroll
            for (int j = 0; j < 16; ++j) {
                int s0 = __builtin_amdgcn_readlane(cv, 16 + j);
                int s1 = __builtin_amdgcn_readlane(cv, 48 + j);
                va[j] = Xu[(uint)(s0 * 64 + lane)];
                vb[j] = Xu[(uint)(s1 * 64 + lane)];
            }
            #pragma unroll
            for (int j = 0; j < 16; ++j) {
                a0 += lo_bf(va[j]); a1 += hi_bf(va[j]);
                b0 += lo_bf(vb[j]); b1 += hi_bf(vb[j]);
            }
        }
        basea += 32; baseb += 32;
    }
    uint oA = (uint)f2b1(a0 * sca) | ((uint)f2b1(a1 * sca) << 16);
    reinterpret_cast<uint*>(X1)[(uint)(n0 * 64 + lane)] = oA;
    if (has1) {
        uint oB = (uint)f2b1(b0 * scb) | ((uint)f2b1(b1 * scb) << 16);
        reinterpret_cast<uint*>(X1)[(uint)((n0 + 1) * 64 + lane)] = oB;
    }
}

// ---------------- aggregation layer 2 (dual-node) ----------------

template <typename CT>
__global__ __launch_bounds__(256) void agg_sum64(
    const ushort* __restrict__ Zs, const int* __restrict__ rowptr,
    const CT* __restrict__ col, const float* __restrict__ dinv,
    float* __restrict__ Y, int nNodes)
{
    int w    = (blockIdx.x * blockDim.x + threadIdx.x) >> 6;
    int lane = threadIdx.x & 63;
    int n0 = w * 2;
    if (n0 >= nNodes) return;
    n0 = __builtin_amdgcn_readfirstlane(n0);
    bool has1 = (n0 + 1) < nNodes;
    int e0a = rowptr[n0];
    int e1a = rowptr[n0 + 1];
    int e1b = has1 ? rowptr[n0 + 2] : e1a;
    float sca = -dinv[n0];
    float scb = -dinv[has1 ? n0 + 1 : n0];

    float fa = 0.f, fb = 0.f;
    int basea = e0a, baseb = e1a;
    while (basea < e1a || baseb < e1b) {
        int half = lane >> 5, sl = lane & 31;
        int idx = half ? (baseb + sl) : (basea + sl);
        int ee  = half ? e1b : e1a;
        bool okl = idx < ee;
        int cvl = (int)col[okl ? idx : 0];
        int cv  = okl ? cvl : nNodes;
        int cnta = e1a - basea, cntb = e1b - baseb;
        {
            ushort va[16], vb[16];
            #pragma unroll
            for (int j = 0; j < 16; ++j) {
                int s0 = __builtin_amdgcn_readlane(cv, j);
                int s1 = __builtin_amdgcn_readlane(cv, 32 + j);
                va[j] = Zs[(uint)(s0 * 64 + lane)];
                vb[j] = Zs[(uint)(s1 * 64 + lane)];
            }
            #pragma unroll
            for (int j = 0; j < 16; ++j) {
                fa += lo_bf((uint)va[j]);
                fb += lo_bf((uint)vb[j]);
            }
        }
        if (cnta > 16 || cntb > 16) {
            ushort va[16], vb[16];
            #pragma unroll
            for (int j = 0; j < 16; ++j) {
                int s0 = __builtin_amdgcn_readlane(cv, 16 + j);
                int s1 = __builtin_amdgcn_readlane(cv, 48 + j);
                va[j] = Zs[(uint)(s0 * 64 + lane)];
                vb[j] = Zs[(uint)(s1 * 64 + lane)];
            }
            #pragma unroll
            for (int j = 0; j < 16; ++j) {
                fa += lo_bf((uint)va[j]);
                fb += lo_bf((uint)vb[j]);
            }
        }
        basea += 32; baseb += 32;
    }
    Y[(uint)(n0 * 64 + lane)] += fa * sca;
    if (has1)
        Y[(uint)((n0 + 1) * 64 + lane)] += fb * scb;
}

// ---------------- MFMA GEMM layer 1: h1 = [featb | x1] @ W1 + b1 ----------------

__global__ __launch_bounds__(256) void gemm_mfma1(
    const ushort* __restrict__ XA, const ushort* __restrict__ XB,
    const ushort* __restrict__ Wt, const float* __restrict__ bias,
    ushort* __restrict__ Y, int nNodes)
{
    __shared__ ushort wlds[128 * 256];
    int t = threadIdx.x;

    #pragma unroll
    for (int it = 0; it < 16; ++it) {
        int i = it * 256 + t;
        int c = i >> 5;
        int o = (i & 31) << 4;
        bf16x8 v = *reinterpret_cast<const bf16x8*>(Wt + ((size_t)c << 8) + (o >> 1));
        *reinterpret_cast<bf16x8*>((char*)wlds + ((size_t)c << 9) + (o ^ ((c & 7) << 4))) = v;
    }
    __syncthreads();

    int wave = t >> 6, lane = t & 63;
    int r16 = lane & 15, g = lane >> 4;
    int nodeBase = blockIdx.x * 128 + wave * 32;

    int arow0 = nodeBase + r16;       if (arow0 > nNodes - 1) arow0 = nNodes - 1;
    int arow1 = nodeBase + 16 + r16;  if (arow1 > nNodes - 1) arow1 = nNodes - 1;
    const ushort* pA0 = XA + (size_t)arow0 * 128;
    const ushort* pA1 = XA + (size_t)arow1 * 128;
    const ushort* pB0 = XB + (size_t)arow0 * 128;
    const ushort* pB1 = XB + (size_t)arow1 * 128;

    f32x4 acc0[8], acc1[8];
    #pragma unroll
    for (int i = 0; i < 8; ++i) { acc0[i] = f32x4{0,0,0,0}; acc1[i] = f32x4{0,0,0,0}; }

    #pragma unroll
    for (int kb = 0; kb < 8; ++kb) {
        int kk = (kb & 3) * 32 + g * 8;
        bf16x8 a0 = *reinterpret_cast<const bf16x8*>(((kb < 4) ? pA0 : pB0) + kk);
        bf16x8 a1 = *reinterpret_cast<const bf16x8*>(((kb < 4) ? pA1 : pB1) + kk);
        int o = kb * 64 + g * 16;
        #pragma unroll
        for (int ct = 0; ct < 8; ++ct) {
            int c = ct * 16 + r16;
            bf16x8 bfrag = *reinterpret_cast<const bf16x8*>(
                (const char*)wlds + ((size_t)c << 9) + (o ^ ((c & 7) << 4)));
            acc0[ct] = __builtin_amdgcn_mfma_f32_16x16x32_bf16(a0, bfrag, acc0[ct], 0, 0, 0);
            acc1[ct] = __builtin_amdgcn_mfma_f32_16x16x32_bf16(a1, bfrag, acc1[ct], 0, 0, 0);
        }
    }

    #pragma unroll
    for (int ct = 0; ct < 8; ++ct) {
        float bv = bias[ct * 16 + r16];
        #pragma unroll
        for (int r = 0; r < 4; ++r) {
            int orow0 = nodeBase + g * 4 + r;
            int orow1 = orow0 + 16;
            if (orow0 < nNodes) Y[(size_t)orow0 * 128 + ct * 16 + r16] = f2b1(acc0[ct][r] + bv);
            if (orow1 < nNodes) Y[(size_t)orow1 * 128 + ct * 16 + r16] = f2b1(acc1[ct][r] + bv);
        }
    }
}

// ---------------- MFMA GEMM layer 2 fused: [y_top | z2s] = h1 @ W2c, K=128 ----------------

__global__ __launch_bounds__(256) void gemm_mfma2(
    const ushort* __restrict__ H1, const ushort* __restrict__ W2ct,
    const float* __restrict__ bias, const float* __restrict__ dinv,
    float* __restrict__ Yout, ushort* __restrict__ Z2, int nNodes)
{
    __shared__ ushort wlds[128 * 128];
    int t = threadIdx.x;

    #pragma unroll
    for (int it = 0; it < 8; ++it) {
        int i = it * 256 + t;
        int c = i >> 4;
        int o = (i & 15) << 4;
        bf16x8 v = *reinterpret_cast<const bf16x8*>(W2ct + ((size_t)c << 7) + (o >> 1));
        *reinterpret_cast<bf16x8*>((char*)wlds + ((size_t)c << 8) + (o ^ ((c & 7) << 4))) = v;
    }
    __syncthreads();

    int wave = t >> 6, lane = t & 63;
    int r16 = lane & 15, g = lane >> 4;
    int nodeBase = blockIdx.x * 128 + wave * 32;

    int arow0 = nodeBase + r16;       if (arow0 > nNodes - 1) arow0 = nNodes - 1;
    int arow1 = nodeBase + 16 + r16;  if (arow1 > nNodes - 1) arow1 = nNodes - 1;
    const ushort* p0 = H1 + (size_t)arow0 * 128;
    const ushort* p1 = H1 + (size_t)arow1 * 128;

    f32x4 acc0[8], acc1[8];
    #pragma unroll
    for (int i = 0; i < 8; ++i) { acc0[i] = f32x4{0,0,0,0}; acc1[i] = f32x4{0,0,0,0}; }

    #pragma unroll
    for (int kb = 0; kb < 4; ++kb) {
        int kk = kb * 32 + g * 8;
        bf16x8 v0 = *reinterpret_cast<const bf16x8*>(p0 + kk);
        bf16x8 v1 = *reinterpret_cast<const bf16x8*>(p1 + kk);
        int o = kb * 64 + g * 16;
        #pragma unroll
        for (int ct = 0; ct < 8; ++ct) {
            int c = ct * 16 + r16;
            bf16x8 bfrag = *reinterpret_cast<const bf16x8*>(
                (const char*)wlds + ((size_t)c << 8) + (o ^ ((c & 7) << 4)));
            acc0[ct] = __builtin_amdgcn_mfma_f32_16x16x32_bf16(v0, bfrag, acc0[ct], 0, 0, 0);
            acc1[ct] = __builtin_amdgcn_mfma_f32_16x16x32_bf16(v1, bfrag, acc1[ct], 0, 0, 0);
        }
    }

    float dv0[4], dv1[4];
    #pragma unroll
    for (int r = 0; r < 4; ++r) {
        int o0 = nodeBase + g * 4 + r;      if (o0 > nNodes - 1) o0 = nNodes - 1;
        int o1 = nodeBase + 16 + g * 4 + r; if (o1 > nNodes - 1) o1 = nNodes - 1;
        dv0[r] = dinv[o0]; dv1[r] = dinv[o1];
    }

    #pragma unroll
    for (int ct = 0; ct < 8; ++ct) {
        float bv = (ct < 4) ? bias[ct * 16 + r16] : 0.f;
        #pragma unroll
        for (int r = 0; r < 4; ++r) {
            int orow0 = nodeBase + g * 4 + r;
            int orow1 = orow0 + 16;
            if (ct < 4) {
                if (orow0 < nNodes) Yout[(size_t)orow0 * 64 + ct * 16 + r16] = acc0[ct][r] + bv;
                if (orow1 < nNodes) Yout[(size_t)orow1 * 64 + ct * 16 + r16] = acc1[ct][r] + bv;
            } else {
                if (orow0 < nNodes) Z2[(size_t)orow0 * 64 + (ct - 4) * 16 + r16] = f2b1(acc0[ct][r] * dv0[r]);
                if (orow1 < nNodes) Z2[(size_t)orow1 * 64 + (ct - 4) * 16 + r16] = f2b1(acc1[ct][r] * dv1[r]);
            }
        }
    }
}

// ---------------- host ----------------

extern "C" void kernel_launch(void* const* d_in, const int* in_sizes, int n_in,
                              void* d_out, int out_size, void* d_ws, size_t ws_size,
                              hipStream_t stream)
{
    const float* feats = (const float*)d_in[0];
    const int*   src   = (const int*)d_in[1];
    const int*   dst   = (const int*)d_in[2];
    const float* W1    = (const float*)d_in[3];
    const float* b1    = (const float*)d_in[4];
    const float* W2    = (const float*)d_in[5];
    const float* b2    = (const float*)d_in[6];
    float* out = (float*)d_out;

    const int N = in_sizes[0] / IN_DIM;
    const int E = in_sizes[1];
    const int NB = (N + 1023) / 1024;

    char* ws = (char*)d_ws;
    size_t off = 0;
    int*    deg    = (int*)(ws + off);    off = align256(off + (size_t)N * 4);
    int*    rowptr = (int*)(ws + off);    off = align256(off + (size_t)(N + 1) * 4);
    int*    pre    = (int*)(ws + off);    off = align256(off + (size_t)N * 4);
    int*    bsum   = (int*)(ws + off);    off = align256(off + (size_t)64 * 4);
    int*    rank   = (int*)(ws + off);    off = align256(off + (size_t)E * 4);
    void*   colv   = (void*)(ws + off);   off = align256(off + (size_t)E * 4);
    float*  dinv   = (float*)(ws + off);  off = align256(off + (size_t)N * 4);
    ushort* featb  = (ushort*)(ws + off); off = align256(off + (size_t)N * 128 * 2);
    ushort* featbs = (ushort*)(ws + off); off = align256(off + (size_t)(N + 1) * 128 * 2);
    ushort* x1b    = (ushort*)(ws + off); off = align256(off + (size_t)N * 128 * 2);
    ushort* h1b    = (ushort*)(ws + off); off = align256(off + (size_t)N * 128 * 2);
    ushort* z2s    = (ushort*)(ws + off); off = align256(off + (size_t)(N + 1) * 64 * 2);
    ushort* W1t    = (ushort*)(ws + off); off = align256(off + (size_t)256 * 128 * 2);
    ushort* W2ct   = (ushort*)(ws + off); off = align256(off + (size_t)128 * 128 * 2);

    const bool small = (N <= 65535);

    // 1) zero deg
    const int n16 = (N + 3) / 4;
    zero_kernel<<<(n16 + 255) / 256, 256, 0, stream>>>((int4*)deg, n16);

    // 2) hist + rank (+ weight conversions hidden under atomic latency)
    const int histBlocks = (E + 255) / 256;
    hist_conv<<<histBlocks + 128 + 64, 256, 0, stream>>>(
        dst, deg, rank, E, histBlocks, W1, W1t, W2, W2ct);

    // 3) chunk prescan
    scan_blocks<<<NB, 256, 0, stream>>>(deg, pre, bsum, N);

    // 4) rowptr + dinv
    scan_add<<<(N + 255) / 256, 256, 0, stream>>>(pre, bsum, deg, rowptr, dinv, N, E, NB);

    // 5) fill CSR + featb/featbs (+ pad rows)
    const int fillBlocks = ((E + 3) / 4 + 255) / 256;
    const int nbF = (N * 32 + 255) / 256;
    if (small)
        phase2_kernel<ushort><<<fillBlocks + nbF + 1, 256, 0, stream>>>(
            src, dst, rowptr, rank, (ushort*)colv, E, fillBlocks,
            feats, dinv, featb, featbs, z2s, N, nbF);
    else
        phase2_kernel<uint><<<fillBlocks + nbF + 1, 256, 0, stream>>>(
            src, dst, rowptr, rank, (uint*)colv, E, fillBlocks,
            feats, dinv, featb, featbs, z2s, N, nbF);

    const int nPairWaves = (N + 1) / 2;
    const int aggBlocks = (nPairWaves * 64 + 255) / 256;
    const int gemmBlocks = (N + 127) / 128;

    // 6) agg1 ; 7) gemm1
    if (small)
        agg_sum128<ushort><<<aggBlocks, 256, 0, stream>>>(featbs, rowptr, (const ushort*)colv, dinv, x1b, N);
    else
        agg_sum128<uint><<<aggBlocks, 256, 0, stream>>>(featbs, rowptr, (const uint*)colv, dinv, x1b, N);
    gemm_mfma1<<<gemmBlocks, 256, 0, stream>>>(featb, x1b, W1t, b1, h1b, N);

    // 8) gemm2 ; 9) agg2
    gemm_mfma2<<<gemmBlocks, 256, 0, stream>>>(h1b, W2ct, b2, dinv, out, z2s, N);
    if (small)
        agg_sum64<ushort><<<aggBlocks, 256, 0, stream>>>(z2s, rowptr, (const ushort*)colv, dinv, out, N);
    else
        agg_sum64<uint><<<aggBlocks, 256, 0, stream>>>(z2s, rowptr, (const uint*)colv, dinv, out, N);
}